// Round 2
// baseline (1080.844 us; speedup 1.0000x reference)
//
#include <hip/hip_runtime.h>

typedef unsigned int u32;

#define BS    16
#define HDIM  2048
#define QL    768
#define KVL   512
#define DR    64
#define DN    128
#define NH    16
#define NIH   8
#define IDXD  128
#define BLK   128
#define BPS   32
#define MAXKV 4096
#define TOPK  1024

// ---------------- 1. cq = rmsnorm(x @ w_dq) ----------------
__global__ void k_cq(const float* __restrict__ x, const float* __restrict__ w,
                     const float* __restrict__ g, float* __restrict__ cq){
  int b = blockIdx.x, t = threadIdx.x;               // 256 threads
  __shared__ float xs[HDIM];
  __shared__ float red[256];
  for (int k=t;k<HDIM;k+=256) xs[k] = x[b*HDIM+k];
  __syncthreads();
  float a0=0.f,a1=0.f,a2=0.f;
  for (int k=0;k<HDIM;k++){
    float xv = xs[k];
    const float* wr = w + (size_t)k*QL;
    a0 += xv*wr[t];
    a1 += xv*wr[t+256];
    a2 += xv*wr[t+512];
  }
  red[t] = a0*a0+a1*a1+a2*a2;
  __syncthreads();
  for (int s=128;s>0;s>>=1){ if(t<s) red[t]+=red[t+s]; __syncthreads(); }
  float scale = 1.0f/sqrtf(red[0]/(float)QL + 1e-6f);
  cq[b*QL+t]     = a0*scale*g[t];
  cq[b*QL+t+256] = a1*scale*g[t+256];
  cq[b*QL+t+512] = a2*scale*g[t+512];
}

// ---------------- 2. ckv (rmsnorm) + kr (rope) -> caches ----------------
__global__ void k_ckvkr(const float* __restrict__ x, const float* __restrict__ w,
                        const float* __restrict__ g, const float* __restrict__ sinp,
                        const float* __restrict__ cosp, const int* __restrict__ cidx,
                        float* __restrict__ kvc, float* __restrict__ krc){
  int b=blockIdx.x, t=threadIdx.x;                   // 256 threads
  __shared__ float xs[HDIM];
  __shared__ float red[256];
  __shared__ float krr[DR];
  for (int k=t;k<HDIM;k+=256) xs[k]=x[b*HDIM+k];
  __syncthreads();
  float a0=0.f,a1=0.f,a2=0.f;
  for(int k=0;k<HDIM;k++){
    float xv=xs[k];
    const float* wr = w + (size_t)k*(KVL+DR);
    a0 += xv*wr[t];
    a1 += xv*wr[t+256];
    a2 += xv*wr[512 + (t&63)];                       // only t<64 uses it
  }
  red[t]=a0*a0+a1*a1;
  __syncthreads();
  for (int s=128;s>0;s>>=1){ if(t<s) red[t]+=red[t+s]; __syncthreads(); }
  float scale = 1.0f/sqrtf(red[0]/(float)KVL + 1e-6f);
  int ci = cidx[b];
  kvc[(size_t)ci*KVL + t]     = a0*scale*g[t];
  kvc[(size_t)ci*KVL + t+256] = a1*scale*g[t+256];
  if (t<DR) krr[t]=a2;
  __syncthreads();
  if (t<DR){
    float v=krr[t];
    float rot = (t<32)? -krr[t+32] : krr[t-32];
    krc[(size_t)ci*DR + t] = v*cosp[b*DR+t] + rot*sinp[b*DR+t];
  }
}

// ---------------- 3. ki = layernorm(x @ w_idx_k) -> index cache ----------------
__global__ void k_ki(const float* __restrict__ x, const float* __restrict__ w,
                     const float* __restrict__ g, const float* __restrict__ be,
                     const int* __restrict__ cidx, float* __restrict__ ikc){
  int b=blockIdx.x, t=threadIdx.x;                   // 128 threads
  __shared__ float xs[HDIM];
  __shared__ float red[128];
  for(int k=t;k<HDIM;k+=128) xs[k]=x[b*HDIM+k];
  __syncthreads();
  float a=0.f;
  for(int k=0;k<HDIM;k++) a += xs[k]*w[(size_t)k*IDXD + t];
  red[t]=a; __syncthreads();
  for(int s=64;s>0;s>>=1){ if(t<s) red[t]+=red[t+s]; __syncthreads(); }
  float mean = red[0]/(float)IDXD;
  __syncthreads();
  float c = a-mean;
  red[t]=c*c; __syncthreads();
  for(int s=64;s>0;s>>=1){ if(t<s) red[t]+=red[t+s]; __syncthreads(); }
  float var = red[0]/(float)IDXD;
  ikc[(size_t)cidx[b]*IDXD + t] = c/sqrtf(var+1e-6f)*g[t] + be[t];
}

// ---------------- 4. q = cq @ w_uq_qr, split nope / rope(pe) ----------------
__global__ void k_q(const float* __restrict__ cq, const float* __restrict__ w,
                    const float* __restrict__ sinp, const float* __restrict__ cosp,
                    float* __restrict__ qn, float* __restrict__ qp){
  int b=blockIdx.x, h=blockIdx.y, t=threadIdx.x;     // 192 threads
  __shared__ float cs[QL];
  __shared__ float qh[192];
  for(int k=t;k<QL;k+=192) cs[k]=cq[b*QL+k];
  __syncthreads();
  float a=0.f;
  int j = h*192 + t;
  for(int k=0;k<QL;k++) a += cs[k]*w[(size_t)k*(NH*192) + j];
  qh[t]=a; __syncthreads();
  if (t<DN) qn[(b*NH+h)*DN + t] = a;
  else {
    int d = t-DN;
    float rot = (d<32)? -qh[DN+d+32] : qh[DN+d-32];
    qp[(b*NH+h)*DR + d] = a*cosp[b*DR+d] + rot*sinp[b*DR+d];
  }
}

// ---------------- 5. q_lat = q_nope · w_uk ----------------
__global__ void k_qlat(const float* __restrict__ qn, const float* __restrict__ wuk,
                       float* __restrict__ ql){
  int b=blockIdx.x,h=blockIdx.y,t=threadIdx.x;       // 256 threads
  __shared__ float q[DN];
  if(t<DN) q[t]=qn[(b*NH+h)*DN+t];
  __syncthreads();
  float a0=0.f,a1=0.f;
  for(int d=0;d<DN;d++){
    const float* wr = wuk + ((size_t)(h*DN+d))*KVL;
    float qv=q[d];
    a0 += qv*wr[t];
    a1 += qv*wr[t+256];
  }
  ql[(b*NH+h)*KVL + t]     = a0;
  ql[(b*NH+h)*KVL + t+256] = a1;
}

// ---------------- 6. qi = cq @ w_idx_qb ; head_w = cq @ w_idx_proj ----------------
__global__ void k_qi(const float* __restrict__ cq, const float* __restrict__ wqb,
                     const float* __restrict__ wproj, float* __restrict__ qi,
                     float* __restrict__ hw){
  int b=blockIdx.x,t=threadIdx.x;                    // 256 threads
  __shared__ float cs[QL];
  for(int k=t;k<QL;k+=256) cs[k]=cq[b*QL+k];
  __syncthreads();
  float a0=0.f,a1=0.f,a2=0.f,a3=0.f;
  for(int k=0;k<QL;k++){
    float cv=cs[k];
    const float* wr = wqb + (size_t)k*(NIH*IDXD);
    a0+=cv*wr[t]; a1+=cv*wr[t+256]; a2+=cv*wr[t+512]; a3+=cv*wr[t+768];
  }
  qi[b*1024+t]=a0; qi[b*1024+t+256]=a1; qi[b*1024+t+512]=a2; qi[b*1024+t+768]=a3;
  if(t<NIH){
    float a=0.f;
    for(int k=0;k<QL;k++) a+=cs[k]*wproj[(size_t)k*NIH+t];
    hw[b*NIH+t]=a;
  }
}

// ---------------- 7. index scores ----------------
__global__ void k_isc(const float* __restrict__ qi, const float* __restrict__ hw,
                      const float* __restrict__ ikc, const int* __restrict__ btab,
                      const int* __restrict__ aseq, float* __restrict__ isc){
  int b=blockIdx.x, jb=blockIdx.y, t=threadIdx.x;    // 128 threads
  __shared__ float K[64*129];                        // 33 KB, +1 pad breaks pow2 stride
  __shared__ float qs[NIH*IDXD];
  __shared__ float hs[NIH];
  int blk = btab[b*BPS+jb];
  for(int m=0;m<8;m++) qs[m*IDXD+t] = qi[b*(NIH*IDXD) + m*IDXD + t];
  if(t<NIH) hs[t]=hw[b*NIH+t];
  const float4* k4 = (const float4*)(ikc + (size_t)blk*BLK*IDXD);
  int as = aseq[b];
  for(int half=0; half<2; half++){
    __syncthreads();
    for(int it=0; it<16; it++){                      // 64 rows x 32 float4
      int idx = it*128 + t;
      int r = idx>>5, c4 = idx&31;
      float4 v = k4[(half*64+r)*32 + c4];
      float* dst = &K[r*129 + c4*4];
      dst[0]=v.x; dst[1]=v.y; dst[2]=v.z; dst[3]=v.w;
    }
    __syncthreads();
    if(t<64){
      float s[NIH];
      #pragma unroll
      for(int h2=0;h2<NIH;h2++) s[h2]=0.f;
      const float* Kr = &K[t*129];
      for(int d=0; d<IDXD; d++){
        float kv = Kr[d];
        #pragma unroll
        for(int h2=0;h2<NIH;h2++) s[h2] += qs[h2*IDXD+d]*kv;
      }
      float sc=0.f;
      #pragma unroll
      for(int h2=0;h2<NIH;h2++) sc += hs[h2]*fmaxf(s[h2],0.f);
      sc *= 0.08838834764831845f;                    // 1/sqrt(128)
      int n = jb*BLK + half*64 + t;
      if (n >= as) sc = -1e9f;
      isc[b*MAXKV + n] = sc;
    }
  }
}

// ---------------- 8. top-1024 of 4096 (stable set selection) ----------------
__global__ void k_topk(const float* __restrict__ isc, const int* __restrict__ btab,
                       int* __restrict__ selp, float* __restrict__ sels){
  int b=blockIdx.x, t=threadIdx.x;                   // 256 threads
  __shared__ u32 su[MAXKV];
  __shared__ u32 red[256];
  __shared__ u32 sGT[256], sEQ[256];
  __shared__ u32 shT;
  for(int k2=0;k2<16;k2++){
    int i=k2*256+t;
    u32 bits=__float_as_uint(isc[b*MAXKV+i]);
    su[i] = (bits & 0x80000000u) ? ~bits : (bits | 0x80000000u);
  }
  __syncthreads();
  u32 lo=0u, hi=0xFFFFFFFFu;
  while(lo<hi){
    u32 mid = lo + ((hi-lo)>>1) + 1u;
    u32 c=0u;
    for(int j=0;j<16;j++) c += (su[t*16+j] >= mid) ? 1u : 0u;
    red[t]=c; __syncthreads();
    for(int s=128;s>0;s>>=1){ if(t<s) red[t]+=red[t+s]; __syncthreads(); }
    u32 cnt=red[0]; __syncthreads();
    if(cnt >= 1024u) lo=mid; else hi=mid-1u;
  }
  u32 T=lo;
  u32 cG=0u,cE=0u;
  for(int j=0;j<16;j++){ u32 u=su[t*16+j]; cG += (u>T)?1u:0u; cE += (u==T)?1u:0u; }
  sGT[t]=cG; sEQ[t]=cE; __syncthreads();
  if(t==0){
    u32 aG=0u,aE=0u;
    for(int i2=0;i2<256;i2++){
      u32 g2=sGT[i2]; sGT[i2]=aG; aG+=g2;
      u32 e2=sEQ[i2]; sEQ[i2]=aE; aE+=e2;
    }
    shT=aG;
  }
  __syncthreads();
  u32 mGT=shT;
  u32 need = 1024u - mGT;
  u32 gG=sGT[t], gE=sEQ[t];
  for(int j=0;j<16;j++){
    int i=t*16+j; u32 u=su[i];
    int slot=-1;
    if(u>T) slot = (int)(gG++);
    else if(u==T){ u32 r=gE++; if(r<need) slot=(int)(mGT+r); }
    if(slot>=0){
      int pos = btab[b*BPS + (i>>7)]*BLK + (i&127);
      selp[b*TOPK+slot]=pos;
      sels[b*TOPK+slot]=isc[b*MAXKV+i];
    }
  }
}

// ---------------- 9. attention scores over selected ----------------
__global__ void k_att(const float* __restrict__ qlat, const float* __restrict__ qpe,
                      const float* __restrict__ kvc, const float* __restrict__ krc,
                      const int* __restrict__ selp, const float* __restrict__ sels,
                      float* __restrict__ att){
  int b=blockIdx.x, ch=blockIdx.y, t=threadIdx.x;    // 256 threads
  __shared__ float qls[NH*513];                       // padded
  __shared__ float qps[NH*65];
  __shared__ int   sp[128];
  __shared__ float sv[128];
  for(int idx=t; idx<NH*KVL; idx+=256){ int r=idx>>9, c=idx&511; qls[r*513+c]=qlat[(b*NH+r)*KVL+c]; }
  for(int idx=t; idx<NH*DR;  idx+=256){ int r=idx>>6, c=idx&63;  qps[r*65+c]=qpe[(b*NH+r)*DR+c]; }
  if(t<128){ sp[t]=selp[b*TOPK + ch*128 + t]; sv[t]=sels[b*TOPK + ch*128 + t]; }
  __syncthreads();
  int h = t>>4, il = t&15;
  const float scale = 0.07216878364870323f;          // 1/sqrt(192)
  for(int rep=0; rep<8; rep++){
    int i = rep*16 + il;
    int pos = sp[i];
    const float4* rowc = (const float4*)(kvc + (size_t)pos*KVL);
    float acc=0.f;
    for(int v=0;v<128;v++){
      float4 u = rowc[v];
      const float* q4 = &qls[h*513 + v*4];
      acc += u.x*q4[0] + u.y*q4[1] + u.z*q4[2] + u.w*q4[3];
    }
    const float4* rowr = (const float4*)(krc + (size_t)pos*DR);
    for(int v=0;v<16;v++){
      float4 u = rowr[v];
      const float* q4 = &qps[h*65 + v*4];
      acc += u.x*q4[0] + u.y*q4[1] + u.z*q4[2] + u.w*q4[3];
    }
    float val = (sv[i] > -1e8f)? acc*scale : -1e9f;
    att[(size_t)(b*NH+h)*TOPK + ch*128 + i] = val;
  }
}

// ---------------- 10. softmax over 1024 ----------------
__global__ void k_soft(float* __restrict__ att){
  int b=blockIdx.x,h=blockIdx.y,t=threadIdx.x;       // 256 threads
  float* a = att + (size_t)(b*NH+h)*TOPK;
  __shared__ float red[256];
  float v[4];
  float m=-1e30f;
  for(int j=0;j<4;j++){ v[j]=a[t+256*j]; m=fmaxf(m,v[j]); }
  red[t]=m; __syncthreads();
  for(int s=128;s>0;s>>=1){ if(t<s) red[t]=fmaxf(red[t],red[t+s]); __syncthreads(); }
  float M=red[0]; __syncthreads();
  float sum=0.f;
  for(int j=0;j<4;j++){ v[j]=expf(v[j]-M); sum+=v[j]; }
  red[t]=sum; __syncthreads();
  for(int s=128;s>0;s>>=1){ if(t<s) red[t]+=red[t+s]; __syncthreads(); }
  float inv=1.0f/red[0];
  for(int j=0;j<4;j++) a[t+256*j]=v[j]*inv;
}

// ---------------- 11. partial o_lat = p · ckv_sel (per 128-chunk) ----------------
__global__ void k_olat(const float* __restrict__ p, const float* __restrict__ kvc,
                       const int* __restrict__ selp, float* __restrict__ opart){
  int b=blockIdx.x, ch=blockIdx.y, t=threadIdx.x;    // 256 threads
  __shared__ float Ks[16*512];                        // 32 KB: 16 rows x 512 f32
  __shared__ float ps[NH*128];                        // 8 KB
  __shared__ int sp[128];
  if(t<128) sp[t]=selp[b*TOPK+ch*128+t];
  for(int m=0;m<8;m++){
    int idx=m*256+t;
    ps[idx]=p[(size_t)(b*NH+(idx>>7))*TOPK + ch*128 + (idx&127)];
  }
  float acc[32];
  #pragma unroll
  for(int m=0;m<32;m++) acc[m]=0.f;
  const float4* kv4=(const float4*)kvc;
  for(int st=0; st<8; st++){
    __syncthreads();
    for(int it=0; it<8; it++){                       // 16 rows x 128 float4
      int idx=it*256+t;
      int r=idx>>7, c4=idx&127;
      float4 v = kv4[(size_t)sp[st*16+r]*128 + c4];
      float* dst=&Ks[r*512 + c4*4];
      dst[0]=v.x; dst[1]=v.y; dst[2]=v.z; dst[3]=v.w;
    }
    __syncthreads();
    #pragma unroll
    for(int m=0;m<32;m++){
      int out=m*256+t; int h=out>>9, c=out&511;
      float a=acc[m];
      const float* pr = &ps[h*128 + st*16];
      #pragma unroll
      for(int i2=0;i2<16;i2++) a += pr[i2]*Ks[i2*512 + c];
      acc[m]=a;
    }
  }
  #pragma unroll
  for(int m=0;m<32;m++){
    int out=m*256+t; int h=out>>9, c=out&511;
    opart[(((size_t)(b*8+ch))*NH + h)*KVL + c] = acc[m];
  }
}

// ---------------- 12. o = (sum opart) · w_uk -> out ----------------
__global__ void k_out(const float* __restrict__ opart, const float* __restrict__ wuk,
                      float* __restrict__ out){
  int b=blockIdx.x,h=blockIdx.y,t=threadIdx.x;       // 128 threads
  __shared__ float ol[KVL];
  for(int m=0;m<4;m++){
    int c=t+128*m;
    float s=0.f;
    for(int chn=0;chn<8;chn++) s += opart[(((size_t)(b*8+chn))*NH+h)*KVL + c];
    ol[c]=s;
  }
  __syncthreads();
  const float4* wr = (const float4*)(wuk + ((size_t)(h*DN+t))*KVL);
  float a=0.f;
  for(int v=0;v<128;v++){
    float4 u = wr[v];
    const float* o4=&ol[v*4];
    a += u.x*o4[0] + u.y*o4[1] + u.z*o4[2] + u.w*o4[3];
  }
  out[b*(NH*DN) + h*DN + t] = a;
}

extern "C" void kernel_launch(void* const* d_in, const int* in_sizes, int n_in,
                              void* d_out, int out_size, void* d_ws, size_t ws_size,
                              hipStream_t stream){
  const float* x        =(const float*)d_in[0];
  const float* w_dq     =(const float*)d_in[1];
  const float* w_uq_qr  =(const float*)d_in[2];
  const float* w_uk     =(const float*)d_in[3];
  const float* w_dkv_kr =(const float*)d_in[4];
  const float* g_cq     =(const float*)d_in[5];
  const float* g_ckv    =(const float*)d_in[6];
  const float* sinp     =(const float*)d_in[7];
  const float* cosp     =(const float*)d_in[8];
  const int*   cidx     =(const int*)d_in[9];
  float*       kvc      =(float*)d_in[10];
  float*       krc      =(float*)d_in[11];
  const int*   btab     =(const int*)d_in[12];
  const int*   aseq     =(const int*)d_in[13];
  const float* w_idx_qb =(const float*)d_in[14];
  const float* w_idx_k  =(const float*)d_in[15];
  const float* w_idx_pj =(const float*)d_in[16];
  const float* g_ik     =(const float*)d_in[17];
  const float* b_ik     =(const float*)d_in[18];
  float*       ikc      =(float*)d_in[19];

  float* ws    = (float*)d_ws;
  float* cq    = ws;               // 16*768      = 12288
  float* qpe   = ws + 12288;       // 16*16*64    = 16384
  float* qnope = ws + 28672;       // 16*16*128   = 32768
  float* qlat  = ws + 61440;       // 16*16*512   = 131072
  float* qi    = ws + 192512;      // 16*8*128    = 16384
  float* hw    = ws + 208896;      // 16*8        = 128
  float* isc   = ws + 209024;      // 16*4096     = 65536
  int*   selp  = (int*)(ws + 274560); // 16*1024  = 16384
  float* sels  = ws + 290944;      // 16*1024     = 16384
  float* att   = ws + 307328;      // 16*16*1024  = 262144
  float* opart = ws + 569472;      // 16*8*16*512 = 1048576

  k_cq   <<<dim3(BS),     dim3(256),0,stream>>>(x,w_dq,g_cq,cq);
  k_ckvkr<<<dim3(BS),     dim3(256),0,stream>>>(x,w_dkv_kr,g_ckv,sinp,cosp,cidx,kvc,krc);
  k_ki   <<<dim3(BS),     dim3(128),0,stream>>>(x,w_idx_k,g_ik,b_ik,cidx,ikc);
  k_q    <<<dim3(BS,NH),  dim3(192),0,stream>>>(cq,w_uq_qr,sinp,cosp,qnope,qpe);
  k_qlat <<<dim3(BS,NH),  dim3(256),0,stream>>>(qnope,w_uk,qlat);
  k_qi   <<<dim3(BS),     dim3(256),0,stream>>>(cq,w_idx_qb,w_idx_pj,qi,hw);
  k_isc  <<<dim3(BS,BPS), dim3(128),0,stream>>>(qi,hw,ikc,btab,aseq,isc);
  k_topk <<<dim3(BS),     dim3(256),0,stream>>>(isc,btab,selp,sels);
  k_att  <<<dim3(BS,8),   dim3(256),0,stream>>>(qlat,qpe,kvc,krc,selp,sels,att);
  k_soft <<<dim3(BS,NH),  dim3(256),0,stream>>>(att);
  k_olat <<<dim3(BS,8),   dim3(256),0,stream>>>(att,kvc,selp,opart);
  k_out  <<<dim3(BS,NH),  dim3(128),0,stream>>>(opart,w_uk,(float*)d_out);
}

// Round 3
// 488.149 us; speedup vs baseline: 2.2142x; 2.2142x over previous
//
#include <hip/hip_runtime.h>

typedef unsigned int u32;

#define BS    16
#define HDIM  2048
#define QL    768
#define KVL   512
#define DR    64
#define DN    128
#define NH    16
#define NIH   8
#define IDXD  128
#define BLK   128
#define BPS   32
#define MAXKV 4096
#define TOPK  1024

// ---------- 1. fused down-proj: y[b, 0:768|768:1344|1344:1472] partials ----------
// grid (23 col-tiles, 4 k-splits), 256 thr
__global__ void k_dproj(const float* __restrict__ x, const float* __restrict__ w_dq,
                        const float* __restrict__ w_dkv, const float* __restrict__ w_ik,
                        float* __restrict__ dpart){
  int tt = blockIdx.x, ks = blockIdx.y, t = threadIdx.x;
  __shared__ float xs[16*512];
  for (int idx=t; idx<16*512; idx+=256){
    int b = idx>>9, kk = idx&511;
    xs[idx] = x[b*HDIM + ks*512 + kk];
  }
  const float* wp; int ld, c0, gbase;
  if (tt < 12){ wp = w_dq;  ld = 768; c0 = tt*64;      gbase = 0; }
  else if (tt < 21){ wp = w_dkv; ld = 576; c0 = (tt-12)*64; gbase = 768; }
  else { wp = w_ik;  ld = 128; c0 = (tt-21)*64; gbase = 1344; }
  int lane = t&63, bg = t>>6;
  int col = c0 + lane;
  __syncthreads();
  float a0=0.f,a1=0.f,a2=0.f,a3=0.f;
  const float* wb = wp + (size_t)(ks*512)*ld + col;
  const float* xb = &xs[bg*4*512];
  for (int kk=0; kk<512; kk++){
    float wv = wb[(size_t)kk*ld];
    a0 += xb[kk]*wv; a1 += xb[512+kk]*wv; a2 += xb[1024+kk]*wv; a3 += xb[1536+kk]*wv;
  }
  int gcol = gbase + col;
  float* dp = dpart + (size_t)(ks*16)*1472;
  dp[(bg*4+0)*1472 + gcol] = a0;
  dp[(bg*4+1)*1472 + gcol] = a1;
  dp[(bg*4+2)*1472 + gcol] = a2;
  dp[(bg*4+3)*1472 + gcol] = a3;
}

// ---------- 2. finalize: rmsnorm cq, rmsnorm ckv, rope kr, layernorm ki, scatter ----------
__global__ void k_dfin(const float* __restrict__ dpart, const float* __restrict__ g_cq,
                       const float* __restrict__ g_ckv, const float* __restrict__ sinp,
                       const float* __restrict__ cosp, const float* __restrict__ g_ik,
                       const float* __restrict__ b_ik, const int* __restrict__ cidx,
                       float* __restrict__ cq, float* __restrict__ kvc,
                       float* __restrict__ krc, float* __restrict__ ikc){
  int b = blockIdx.x, t = threadIdx.x;   // 256
  __shared__ float val[1472];
  __shared__ float red[256];
  for (int c=t; c<1472; c+=256){
    float s = 0.f;
    for (int ks2=0; ks2<4; ks2++) s += dpart[((size_t)ks2*16+b)*1472 + c];
    val[c] = s;
  }
  __syncthreads();
  float c0v = val[t], c1v = val[t+256], c2v = val[t+512];
  red[t] = c0v*c0v + c1v*c1v + c2v*c2v;
  __syncthreads();
  for (int s=128;s>0;s>>=1){ if(t<s) red[t]+=red[t+s]; __syncthreads(); }
  float scq = 1.0f/sqrtf(red[0]/(float)QL + 1e-6f);
  __syncthreads();
  float v0 = val[768+t], v1 = val[1024+t];
  red[t] = v0*v0 + v1*v1;
  __syncthreads();
  for (int s=128;s>0;s>>=1){ if(t<s) red[t]+=red[t+s]; __syncthreads(); }
  float sckv = 1.0f/sqrtf(red[0]/(float)KVL + 1e-6f);
  __syncthreads();
  red[t] = (t<128)? val[1344+t] : 0.f;
  __syncthreads();
  for (int s=128;s>0;s>>=1){ if(t<s) red[t]+=red[t+s]; __syncthreads(); }
  float mean = red[0]/(float)IDXD;
  __syncthreads();
  float cc = (t<128)? (val[1344+t]-mean) : 0.f;
  red[t] = cc*cc;
  __syncthreads();
  for (int s=128;s>0;s>>=1){ if(t<s) red[t]+=red[t+s]; __syncthreads(); }
  float var = red[0]/(float)IDXD;
  int ci = cidx[b];
  cq[b*QL+t]     = c0v*scq*g_cq[t];
  cq[b*QL+t+256] = c1v*scq*g_cq[t+256];
  cq[b*QL+t+512] = c2v*scq*g_cq[t+512];
  kvc[(size_t)ci*KVL + t]     = v0*sckv*g_ckv[t];
  kvc[(size_t)ci*KVL + t+256] = v1*sckv*g_ckv[t+256];
  if (t<DR){
    float v = val[1280+t];
    float rot = (t<32)? -val[1280+t+32] : val[1280+t-32];
    krc[(size_t)ci*DR + t] = v*cosp[b*DR+t] + rot*sinp[b*DR+t];
  }
  if (t<IDXD){
    ikc[(size_t)ci*IDXD + t] = cc/sqrtf(var+1e-6f)*g_ik[t] + b_ik[t];
  }
}

// ---------- 3. fused q-level proj: w_uq_qr (rope fused) | w_idx_qb | w_idx_proj ----------
// grid 65 blocks, 256 thr
__global__ void k_qall(const float* __restrict__ cq, const float* __restrict__ w_uq,
                       const float* __restrict__ w_qb, const float* __restrict__ w_pj,
                       const float* __restrict__ sinp, const float* __restrict__ cosp,
                       float* __restrict__ qn, float* __restrict__ qp,
                       float* __restrict__ qi, float* __restrict__ hw){
  int tt = blockIdx.x, t = threadIdx.x;
  __shared__ float xs[16*768];     // 48 KB
  __shared__ float tile[16*64];    // 4 KB (rope exchange)
  for (int idx=t; idx<16*768; idx+=256) xs[idx] = cq[idx];
  const float* wp; int ld, c0, kind;
  if (tt < 48){ wp=w_uq; ld=3072; c0=tt*64; kind = ((tt%3)==2)?1:0; }
  else if (tt < 64){ wp=w_qb; ld=1024; c0=(tt-48)*64; kind=2; }
  else { wp=w_pj; ld=8; c0=0; kind=3; }
  int lane = t&63, bg = t>>6;
  int col = c0 + lane;
  __syncthreads();
  float a[4] = {0.f,0.f,0.f,0.f};
  if (kind!=3 || lane<8){
    const float* wb = wp + col;
    const float* xb = &xs[bg*4*768];
    for (int k=0;k<768;k++){
      float wv = wb[(size_t)k*ld];
      a[0] += xb[k]*wv; a[1] += xb[768+k]*wv; a[2] += xb[1536+k]*wv; a[3] += xb[2304+k]*wv;
    }
  }
  if (kind==0){
    int h = col/192, j = col%192;   // j < 128
    for (int jj=0;jj<4;jj++) qn[((bg*4+jj)*NH+h)*DN + j] = a[jj];
  } else if (kind==1){
    int h = tt/3, d = lane;
    for (int jj=0;jj<4;jj++) tile[(bg*4+jj)*64 + d] = a[jj];
    __syncthreads();
    for (int jj=0;jj<4;jj++){
      int b = bg*4+jj;
      float v = tile[b*64+d];
      float rot = (d<32)? -tile[b*64+d+32] : tile[b*64+d-32];
      qp[(b*NH+h)*DR + d] = v*cosp[b*DR+d] + rot*sinp[b*DR+d];
    }
  } else if (kind==2){
    for (int jj=0;jj<4;jj++) qi[(bg*4+jj)*1024 + col] = a[jj];
  } else {
    if (lane<8) for (int jj=0;jj<4;jj++) hw[(bg*4+jj)*NIH + lane] = a[jj];
  }
}

// ---------- 4. q_lat = q_nope · w_uk  (batch-stationary) ----------
// grid (16 h, 4 col-tiles), 256 thr
__global__ void k_qlat(const float* __restrict__ qn, const float* __restrict__ wuk,
                       float* __restrict__ ql){
  int h = blockIdx.x, ct = blockIdx.y, t = threadIdx.x;
  __shared__ float qs[16*128];     // 8 KB
  for (int idx=t; idx<2048; idx+=256)
    qs[idx] = qn[((idx>>7)*NH + h)*DN + (idx&127)];
  int col = ct*128 + (t&127), bg = t>>7;   // bg 0..1, 8 batches each
  __syncthreads();
  float acc[8];
  #pragma unroll
  for (int j=0;j<8;j++) acc[j]=0.f;
  const float* wb = wuk + (size_t)(h*DN)*KVL + col;
  for (int d=0; d<DN; d++){
    float wv = wb[(size_t)d*KVL];
    #pragma unroll
    for (int j=0;j<8;j++) acc[j] += qs[(bg*8+j)*DN + d]*wv;
  }
  #pragma unroll
  for (int j=0;j<8;j++) ql[((bg*8+j)*NH+h)*KVL + col] = acc[j];
}

// ---------- 5. index scores ----------
// grid (16, 32), 256 thr
__global__ void k_isc(const float* __restrict__ qi, const float* __restrict__ hw,
                      const float* __restrict__ ikc, const int* __restrict__ btab,
                      const int* __restrict__ aseq, float* __restrict__ isc){
  int b=blockIdx.x, jb=blockIdx.y, t=threadIdx.x;
  __shared__ float K[64*129];       // 33 KB
  __shared__ float qs[NIH*130];     // padded
  __shared__ float hs[NIH];
  __shared__ float red[64*4];
  int blk = btab[b*BPS+jb];
  for (int idx=t; idx<NIH*IDXD; idx+=256){ int h2=idx>>7, d=idx&127; qs[h2*130+d]=qi[b*1024+idx]; }
  if (t<NIH) hs[t]=hw[b*NIH+t];
  const float4* k4 = (const float4*)(ikc + (size_t)blk*BLK*IDXD);
  int as = aseq[b];
  int r = t>>2, hp = t&3;
  for (int half=0; half<2; half++){
    __syncthreads();
    for (int it=0; it<8; it++){
      int idx = it*256 + t;
      int rr = idx>>5, c4 = idx&31;
      float4 v = k4[(half*64+rr)*32 + c4];
      float* dst = &K[rr*129 + c4*4];
      dst[0]=v.x; dst[1]=v.y; dst[2]=v.z; dst[3]=v.w;
    }
    __syncthreads();
    float s0=0.f, s1=0.f;
    const float* Kr = &K[r*129];
    const float* q0 = &qs[hp*130];
    const float* q1 = &qs[(hp+4)*130];
    for (int d=0; d<IDXD; d++){
      float kv = Kr[d];
      s0 += q0[d]*kv; s1 += q1[d]*kv;
    }
    red[r*4+hp] = hs[hp]*fmaxf(s0,0.f) + hs[hp+4]*fmaxf(s1,0.f);
    __syncthreads();
    if (t<64){
      float sc = (red[t*4]+red[t*4+1]+red[t*4+2]+red[t*4+3]) * 0.08838834764831845f;
      int n = jb*BLK + half*64 + t;
      if (n >= as) sc = -1e9f;
      isc[b*MAXKV + n] = sc;
    }
  }
}

// ---------- 6. top-1024 via 4-pass radix select ----------
__global__ void k_topk(const float* __restrict__ isc, const int* __restrict__ btab,
                       int* __restrict__ selp, float* __restrict__ sels){
  int b=blockIdx.x, t=threadIdx.x;   // 256
  __shared__ u32 su[MAXKV];
  __shared__ u32 hist[256];
  __shared__ u32 cum[256];
  __shared__ u32 sGT[256], sEQ[256];
  __shared__ u32 sh_b, sh_mGT;
  for (int k2=0;k2<16;k2++){
    int i=k2*256+t;
    u32 bits=__float_as_uint(isc[b*MAXKV+i]);
    su[i] = (bits & 0x80000000u) ? ~bits : (bits | 0x80000000u);
  }
  u32 prefix=0u, need=1024u;
  for (int shift=24; shift>=0; shift-=8){
    hist[t]=0u;
    __syncthreads();
    u32 hm = (shift==24)? 0u : (0xFFFFFFFFu << (shift+8));
    for (int j=0;j<16;j++){
      u32 u = su[t*16+j];
      if ((u & hm) == prefix) atomicAdd(&hist[(u>>shift)&255u], 1u);
    }
    __syncthreads();
    u32 v = hist[t];
    cum[t]=v;
    __syncthreads();
    for (int off=1; off<256; off<<=1){
      u32 w = (t+off<256)? cum[t+off] : 0u;
      __syncthreads();
      v += w; cum[t]=v;
      __syncthreads();
    }
    u32 above = (t<255)? cum[t+1] : 0u;
    if (cum[t] >= need && above < need) sh_b = (u32)t;
    __syncthreads();
    u32 B = sh_b;
    u32 aboveB = (B<255u)? cum[B+1] : 0u;
    need -= aboveB;
    prefix |= (B<<shift);
    __syncthreads();
  }
  u32 T = prefix;
  u32 cG=0u,cE=0u;
  for (int j=0;j<16;j++){ u32 u=su[t*16+j]; cG += (u>T)?1u:0u; cE += (u==T)?1u:0u; }
  sGT[t]=cG; sEQ[t]=cE;
  __syncthreads();
  if (t==0){
    u32 aG=0u,aE=0u;
    for (int i2=0;i2<256;i2++){
      u32 g2=sGT[i2]; sGT[i2]=aG; aG+=g2;
      u32 e2=sEQ[i2]; sEQ[i2]=aE; aE+=e2;
    }
    sh_mGT=aG;
  }
  __syncthreads();
  u32 mGT=sh_mGT;
  u32 keepEq = 1024u - mGT;
  u32 gG=sGT[t], gE=sEQ[t];
  for (int j=0;j<16;j++){
    int i=t*16+j; u32 u=su[i];
    int slot=-1;
    if (u>T) slot=(int)(gG++);
    else if (u==T){ u32 r2=gE++; if (r2<keepEq) slot=(int)(mGT+r2); }
    if (slot>=0){
      int pos = btab[b*BPS + (i>>7)]*BLK + (i&127);
      selp[b*TOPK+slot]=pos;
      sels[b*TOPK+slot]=isc[b*MAXKV+i];
    }
  }
}

// ---------- 7. attention scores ----------
// grid (16, 64), 256 thr: 16 rows staged, thread=(h, row)
__global__ void k_att(const float* __restrict__ qlat, const float* __restrict__ qpe,
                      const float* __restrict__ kvc, const float* __restrict__ krc,
                      const int* __restrict__ selp, const float* __restrict__ sels,
                      float* __restrict__ att){
  int b=blockIdx.x, rt=blockIdx.y, t=threadIdx.x;
  __shared__ float K[16*580];       // 37.1 KB (512 kv + 64 kr + pad)
  __shared__ int sp16[16];
  __shared__ float sv16[16];
  int base = rt*16;
  if (t<16){ sp16[t]=selp[b*TOPK+base+t]; sv16[t]=sels[b*TOPK+base+t]; }
  __syncthreads();
  const float4* kv4=(const float4*)kvc;
  const float4* kr4=(const float4*)krc;
  for (int idx=t; idx<16*128; idx+=256){
    int r=idx>>7, c4=idx&127;
    float4 v = kv4[(size_t)sp16[r]*128 + c4];
    float* dst=&K[r*580 + c4*4];
    dst[0]=v.x; dst[1]=v.y; dst[2]=v.z; dst[3]=v.w;
  }
  for (int idx=t; idx<16*16; idx+=256){
    int r=idx>>4, c4=idx&15;
    float4 v = kr4[(size_t)sp16[r]*16 + c4];
    float* dst=&K[r*580 + 512 + c4*4];
    dst[0]=v.x; dst[1]=v.y; dst[2]=v.z; dst[3]=v.w;
  }
  __syncthreads();
  int h=t>>4, i=t&15;
  const float4* Kr4 = (const float4*)&K[i*580];
  const float4* qc = (const float4*)(qlat + ((size_t)b*NH+h)*KVL);
  float acc=0.f;
  for (int v=0; v<128; v++){
    float4 q = qc[v]; float4 kk = Kr4[v];
    acc += kk.x*q.x + kk.y*q.y + kk.z*q.z + kk.w*q.w;
  }
  const float4* qp4 = (const float4*)(qpe + ((size_t)b*NH+h)*DR);
  for (int v=0; v<16; v++){
    float4 q = qp4[v]; float4 kk = Kr4[128+v];
    acc += kk.x*q.x + kk.y*q.y + kk.z*q.z + kk.w*q.w;
  }
  float val = (sv16[i] > -1e8f)? acc*0.07216878364870323f : -1e9f;
  att[((size_t)b*NH+h)*TOPK + base + i] = val;
}

// ---------- 8. softmax ----------
__global__ void k_soft(float* __restrict__ att){
  int b=blockIdx.x,h=blockIdx.y,t=threadIdx.x;
  float* a = att + (size_t)(b*NH+h)*TOPK;
  __shared__ float red[256];
  float v[4];
  float m=-1e30f;
  for (int j=0;j<4;j++){ v[j]=a[t+256*j]; m=fmaxf(m,v[j]); }
  red[t]=m; __syncthreads();
  for (int s=128;s>0;s>>=1){ if(t<s) red[t]=fmaxf(red[t],red[t+s]); __syncthreads(); }
  float M=red[0]; __syncthreads();
  float sum=0.f;
  for (int j=0;j<4;j++){ v[j]=expf(v[j]-M); sum+=v[j]; }
  red[t]=sum; __syncthreads();
  for (int s=128;s>0;s>>=1){ if(t<s) red[t]+=red[t+s]; __syncthreads(); }
  float inv=1.0f/red[0];
  for (int j=0;j<4;j++) a[t+256*j]=v[j]*inv;
}

// ---------- 9. o_lat partials: p · ckv_sel ----------
// grid (16 b, 8 ch, 2 half), 256 thr: thread = (4 heads, 4 cols)
__global__ void k_olat(const float* __restrict__ p, const float* __restrict__ kvc,
                       const int* __restrict__ selp, float* __restrict__ opart){
  int b=blockIdx.x, ch=blockIdx.y, half=blockIdx.z, t=threadIdx.x;
  __shared__ float Ks[32*260];      // 33.3 KB
  __shared__ float ps[NH*128];      // 8 KB
  __shared__ int sp[128];
  if (t<128) sp[t]=selp[b*TOPK+ch*128+t];
  for (int idx=t; idx<NH*128; idx+=256)
    ps[idx]=p[((size_t)b*NH+(idx>>7))*TOPK + ch*128 + (idx&127)];
  int c4 = t&63, hg = t>>6;
  float ax[4]={0,0,0,0}, ay[4]={0,0,0,0}, az[4]={0,0,0,0}, aw[4]={0,0,0,0};
  const float4* kv4=(const float4*)kvc;
  const float4* Ks4=(const float4*)Ks;
  for (int st=0; st<4; st++){
    __syncthreads();
    for (int idx=t; idx<32*64; idx+=256){
      int r=idx>>6, cc=idx&63;
      float4 v = kv4[(size_t)sp[st*32+r]*128 + half*64 + cc];
      ((float4*)&Ks[r*260])[cc] = v;
    }
    __syncthreads();
    for (int rr=0; rr<32; rr++){
      float4 kk = Ks4[rr*65 + c4];
      int row = st*32+rr;
      #pragma unroll
      for (int j=0;j<4;j++){
        float pv = ps[(hg*4+j)*128 + row];
        ax[j] += pv*kk.x; ay[j] += pv*kk.y; az[j] += pv*kk.z; aw[j] += pv*kk.w;
      }
    }
  }
  #pragma unroll
  for (int j=0;j<4;j++){
    int h = hg*4+j;
    float* dst = opart + (((size_t)(b*8+ch))*NH + h)*KVL + half*256 + c4*4;
    dst[0]=ax[j]; dst[1]=ay[j]; dst[2]=az[j]; dst[3]=aw[j];
  }
}

// ---------- 10. reduce opart -> olat ----------
__global__ void k_ored(const float* __restrict__ opart, float* __restrict__ olat){
  int b=blockIdx.x, h=blockIdx.y, t=threadIdx.x;
  for (int m=0;m<2;m++){
    int c=t+256*m;
    float s=0.f;
    for (int ch=0;ch<8;ch++) s += opart[(((size_t)(b*8+ch))*NH+h)*KVL + c];
    olat[((size_t)b*NH+h)*KVL + c] = s;
  }
}

// ---------- 11. out = olat · w_uk^T (batch-stationary, staged w tile) ----------
// grid (16 h, 2 d-tiles), 256 thr
__global__ void k_out(const float* __restrict__ olat, const float* __restrict__ wuk,
                      float* __restrict__ out){
  int h=blockIdx.x, dt=blockIdx.y, t=threadIdx.x;
  __shared__ float ol[16*512];      // 32 KB
  __shared__ float wsd[64*68];      // 17.4 KB
  for (int idx=t; idx<16*512; idx+=256)
    ol[idx] = olat[((size_t)(idx>>9)*NH + h)*KVL + (idx&511)];
  int lane=t&63, bg=t>>6;
  int dd = dt*64 + lane;
  float acc[4]={0,0,0,0};
  const float4* w4 = (const float4*)wuk;
  for (int kc=0; kc<8; kc++){
    __syncthreads();
    for (int idx=t; idx<64*16; idx+=256){
      int r=idx>>4, c4=idx&15;
      float4 v = w4[(size_t)(h*DN + dt*64 + r)*128 + kc*16 + c4];
      float* dst=&wsd[r*68 + c4*4];
      dst[0]=v.x; dst[1]=v.y; dst[2]=v.z; dst[3]=v.w;
    }
    __syncthreads();
    for (int kk=0; kk<64; kk++){
      float wv = wsd[lane*68 + kk];
      int k = kc*64+kk;
      #pragma unroll
      for (int j=0;j<4;j++) acc[j] += ol[(bg*4+j)*512 + k]*wv;
    }
  }
  #pragma unroll
  for (int j=0;j<4;j++) out[(bg*4+j)*(NH*DN) + h*DN + dd] = acc[j];
}

extern "C" void kernel_launch(void* const* d_in, const int* in_sizes, int n_in,
                              void* d_out, int out_size, void* d_ws, size_t ws_size,
                              hipStream_t stream){
  const float* x        =(const float*)d_in[0];
  const float* w_dq     =(const float*)d_in[1];
  const float* w_uq_qr  =(const float*)d_in[2];
  const float* w_uk     =(const float*)d_in[3];
  const float* w_dkv_kr =(const float*)d_in[4];
  const float* g_cq     =(const float*)d_in[5];
  const float* g_ckv    =(const float*)d_in[6];
  const float* sinp     =(const float*)d_in[7];
  const float* cosp     =(const float*)d_in[8];
  const int*   cidx     =(const int*)d_in[9];
  float*       kvc      =(float*)d_in[10];
  float*       krc      =(float*)d_in[11];
  const int*   btab     =(const int*)d_in[12];
  const int*   aseq     =(const int*)d_in[13];
  const float* w_idx_qb =(const float*)d_in[14];
  const float* w_idx_k  =(const float*)d_in[15];
  const float* w_idx_pj =(const float*)d_in[16];
  const float* g_ik     =(const float*)d_in[17];
  const float* b_ik     =(const float*)d_in[18];
  float*       ikc      =(float*)d_in[19];

  float* ws    = (float*)d_ws;
  float* cq    = ws;                  // 12288
  float* qpe   = ws + 12288;          // 16384
  float* qnope = ws + 28672;          // 32768
  float* qlat  = ws + 61440;          // 131072
  float* qi    = ws + 192512;         // 16384
  float* hw    = ws + 208896;         // 128
  float* isc   = ws + 209024;         // 65536
  int*   selp  = (int*)(ws + 274560); // 16384
  float* sels  = ws + 290944;         // 16384
  float* att   = ws + 307328;         // 262144
  float* opart = ws + 569472;         // 1048576
  float* olat  = ws + 1618048;        // 131072
  float* dpart = ws + 307328;         // aliases att (dead before k_att)

  k_dproj<<<dim3(23,4),   dim3(256),0,stream>>>(x,w_dq,w_dkv_kr,w_idx_k,dpart);
  k_dfin <<<dim3(BS),     dim3(256),0,stream>>>(dpart,g_cq,g_ckv,sinp,cosp,g_ik,b_ik,cidx,cq,kvc,krc,ikc);
  k_qall <<<dim3(65),     dim3(256),0,stream>>>(cq,w_uq_qr,w_idx_qb,w_idx_pj,sinp,cosp,qnope,qpe,qi,hw);
  k_qlat <<<dim3(16,4),   dim3(256),0,stream>>>(qnope,w_uk,qlat);
  k_isc  <<<dim3(BS,BPS), dim3(256),0,stream>>>(qi,hw,ikc,btab,aseq,isc);
  k_topk <<<dim3(BS),     dim3(256),0,stream>>>(isc,btab,selp,sels);
  k_att  <<<dim3(BS,64),  dim3(256),0,stream>>>(qlat,qpe,kvc,krc,selp,sels,att);
  k_soft <<<dim3(BS,NH),  dim3(256),0,stream>>>(att);
  k_olat <<<dim3(BS,8,2), dim3(256),0,stream>>>(att,kvc,selp,opart);
  k_ored <<<dim3(BS,NH),  dim3(256),0,stream>>>(opart,olat);
  k_out  <<<dim3(16,2),   dim3(256),0,stream>>>(olat,w_uk,(float*)d_out);
}